// Round 3
// baseline (4696.642 us; speedup 1.0000x reference)
//
#include <hip/hip_runtime.h>
#include <hip/hip_fp16.h>

#define AGENT __HIP_MEMORY_SCOPE_AGENT

typedef _Float16 v8h __attribute__((ext_vector_type(8)));
typedef float    v4f __attribute__((ext_vector_type(4)));
typedef unsigned int uint;
typedef uint     v4u __attribute__((ext_vector_type(4)));

// ---- workspace map (bytes). WS_CORE <= 24,510,720 (proven available: round-1
// kernel required that much and passed). encH optional.
#define OFF_KEYSH  0UL            // half [128 b][128 u][256 s]      8,388,608
#define OFF_WBT    8388608UL      // half [1024 c][768 k]            1,572,864
#define OFF_WCT    9961472UL      // half [1024 c][512 k]            1,048,576
#define OFF_W1T    11010048UL     // f32  [128 u][512 e]               262,144
#define OFF_W2H    11272192UL     // half [256 k][128 u]                65,536
#define OFF_EH     11337728UL     // half [48 t][128 b][1024 c]     12,582,912
#define OFF_LIN    23920640UL     // uint [128 b][256 dw] (ctx fp16)   131,072
#define OFF_H1     24051712UL     // uint [2][128][128]                131,072
#define OFF_H2     24182784UL     // uint [2][128][128]                131,072
#define OFF_PRED   24313856UL     // f32  [48 t][128 b]                 24,576
#define OFF_CNT    24338432UL     // int[256]                            1,024
#define WS_CORE    24339456UL
#define OFF_ENCH   24339456UL     // half [128][256][512]           33,554,432
#define WS_FULL    57893888UL

// 16B loads/stores that bypass L1/L2 (coherent at MALL) — the exchange path.
#define GLOAD4(dst, ptr) asm volatile("global_load_dwordx4 %0, %1, off sc0 sc1" : "=v"(dst) : "v"(ptr) : "memory")
#define GSTORE1(ptr, val) asm volatile("global_store_dword %0, %1, off sc0 sc1" :: "v"(ptr), "v"(val) : "memory")
#define VMWAIT() asm volatile("s_waitcnt vmcnt(0)" ::: "memory")

static __device__ __forceinline__ float fast_tanh(float x){
    float e = __expf(2.0f*x);
    return 1.0f - 2.0f*__builtin_amdgcn_rcpf(e + 1.0f);
}
static __device__ __forceinline__ float fast_sigm(float x){
    return __builtin_amdgcn_rcpf(1.0f + __expf(-x));
}

// Fence-free grid barrier (no L2 invalidation -> read-only data stays cached).
static __device__ __forceinline__ void gbar(int* cnt, int idx, int nblk){
    __builtin_amdgcn_s_waitcnt(0);
    __syncthreads();
    if(threadIdx.x == 0){
        __hip_atomic_fetch_add(&cnt[idx], 1, __ATOMIC_RELAXED, AGENT);
        while(__hip_atomic_load(&cnt[idx], __ATOMIC_RELAXED, AGENT) < nblk)
            __builtin_amdgcn_s_sleep(1);
    }
    __syncthreads();
}

// ---------------- tiled transposes: Wbt, Wct, W1t (LDS 32x32, coalesced) ----
__global__ __launch_bounds__(256) void tpose_kernel(
    const float* __restrict__ Wx1, const float* __restrict__ Wh1,
    const float* __restrict__ Wx2, const float* __restrict__ Wh2,
    const float* __restrict__ W1,
    __half* __restrict__ WbtH, __half* __restrict__ WctH, float* __restrict__ W1t)
{
    __shared__ float T[32][33];
    const int bid = blockIdx.x, tid = threadIdx.x;
    if(bid < 768){                              // Wbt: k 768 x n 1024
        const int kt = bid >> 5, nt = bid & 31;
        const int k0 = kt*32, n0 = nt*32;
        const int ty = tid >> 5, tx = tid & 31;
        for(int r = 0; r < 4; ++r){
            int k = k0 + ty*4 + r, n = n0 + tx;
            float v = (k < 512) ? Wx1[(size_t)(256+k)*1024 + n] : Wh1[(size_t)(k-512)*1024 + n];
            T[ty*4 + r][tx] = v;
        }
        __syncthreads();
        const int nl = tid >> 3, kc = tid & 7;
        const int n = n0 + nl;
        const int c = 4*(n & 255) + (n >> 8);
        __half h[4];
        for(int j = 0; j < 4; ++j) h[j] = __float2half(T[kc*4 + j][nl]);
        *(uint2*)&WbtH[(size_t)c*768 + k0 + kc*4] = *(uint2*)h;
    } else if(bid < 1280){                      // Wct: k 512 x n 1024
        const int i = bid - 768;
        const int kt = i >> 5, nt = i & 31;
        const int k0 = kt*32, n0 = nt*32;
        const int ty = tid >> 5, tx = tid & 31;
        for(int r = 0; r < 4; ++r){
            int k = k0 + ty*4 + r, n = n0 + tx;
            float v = (k < 256) ? Wx2[(size_t)k*1024 + n] : Wh2[(size_t)(k-256)*1024 + n];
            T[ty*4 + r][tx] = v;
        }
        __syncthreads();
        const int nl = tid >> 3, kc = tid & 7;
        const int n = n0 + nl;
        const int c = 4*(n & 255) + (n >> 8);
        __half h[4];
        for(int j = 0; j < 4; ++j) h[j] = __float2half(T[kc*4 + j][nl]);
        *(uint2*)&WctH[(size_t)c*512 + k0 + kc*4] = *(uint2*)h;
    } else {                                    // W1t: [u][e] <- W1[e 512][u 128]
        const int i = bid - 1280;
        const int ut = i >> 4, et = i & 15;
        const int e0 = et*32, u0 = ut*32;
        const int ty = tid >> 5, tx = tid & 31;
        for(int r = 0; r < 4; ++r){
            int e = e0 + ty*4 + r, u = u0 + tx;
            T[ty*4 + r][tx] = W1[(size_t)e*128 + u];
        }
        __syncthreads();
        const int ul = tid >> 3, ec = tid & 7;
        float4 f;
        f.x = T[ec*4+0][ul]; f.y = T[ec*4+1][ul]; f.z = T[ec*4+2][ul]; f.w = T[ec*4+3][ul];
        *(float4*)&W1t[(size_t)(u0+ul)*512 + e0 + ec*4] = f;
    }
}

// ---------------- pack: states, predacc, cnt, W2h, encH (all coalesced) -----
__global__ __launch_bounds__(256) void pack_kernel(
    const float* __restrict__ h1_in, const float* __restrict__ h2_in,
    const float* __restrict__ W2, const float* __restrict__ enc,
    uint* __restrict__ h1d, uint* __restrict__ h2d,
    float* __restrict__ predacc, int* __restrict__ cnt,
    __half* __restrict__ W2h, __half* __restrict__ encH, long long total)
{
    long long id0 = (long long)blockIdx.x*blockDim.x + threadIdx.x;
    long long stride = (long long)gridDim.x*blockDim.x;
    for(long long id = id0; id < total; id += stride){
        if(id < 16384LL){
            int b = (int)(id >> 7), j = (int)(id & 127);
            __half2 p = __floats2half2_rn(h1_in[b*256 + 2*j], h1_in[b*256 + 2*j + 1]);
            h1d[id] = __builtin_bit_cast(uint, p);
        } else if(id < 32768LL){
            long long i = id - 16384LL;
            int b = (int)(i >> 7), j = (int)(i & 127);
            __half2 p = __floats2half2_rn(h2_in[b*256 + 2*j], h2_in[b*256 + 2*j + 1]);
            h2d[i] = __builtin_bit_cast(uint, p);
        } else if(id < 38912LL){
            predacc[(int)(id - 32768LL)] = 0.0f;
        } else if(id < 39168LL){
            cnt[(int)(id - 38912LL)] = 0;
        } else if(id < 71936LL){
            long long i = id - 39168LL;
            W2h[i] = __float2half(W2[i]);
        } else {
            long long c = id - 71936LL;          // float4 chunks of enc
            float4 f = *(const float4*)&enc[c*4];
            __half2 p0 = __floats2half2_rn(f.x, f.y);
            __half2 p1 = __floats2half2_rn(f.z, f.w);
            uint2 u; u.x = __builtin_bit_cast(uint, p0); u.y = __builtin_bit_cast(uint, p1);
            *(uint2*)&encH[c*4] = u;
        }
    }
}

// ---------------- E = relu(x*embW+embb) @ Wx1[0:256] + bl1, interleaved cols
__global__ __launch_bounds__(256) void embE_kernel(
    const float* __restrict__ xdec, const float* __restrict__ embW, const float* __restrict__ embb,
    const float* __restrict__ Wx1, const float* __restrict__ bl1, __half* __restrict__ Eh)
{
    __shared__ float embS[32][256];
    const int RT = blockIdx.x >> 2, CT = blockIdx.x & 3;
    const int R0 = RT*64, tid = threadIdx.x;
    const int col = CT*256 + tid;
    const int n = (col & 3)*256 + (col >> 2);    // interleaved col -> original z col
    const float bln = bl1[n];
    const float ew = embW[tid], eb = embb[tid];
    for(int rb2 = 0; rb2 < 64; rb2 += 32){
        for(int r = 0; r < 32; ++r){
            int R = R0 + rb2 + r;
            int t = R >> 7, b = R & 127;
            float x = xdec[b*48 + t];
            embS[r][tid] = fmaxf(x*ew + eb, 0.0f);
        }
        __syncthreads();
        for(int rb = 0; rb < 32; rb += 16){
            float acc[16];
            #pragma unroll
            for(int r = 0; r < 16; ++r) acc[r] = 0.0f;
            for(int j = 0; j < 256; ++j){
                float wv = Wx1[(size_t)j*1024 + n];
                #pragma unroll
                for(int r = 0; r < 16; ++r) acc[r] += embS[rb + r][j]*wv;
            }
            #pragma unroll
            for(int r = 0; r < 16; ++r){
                int R = R0 + rb2 + rb + r;
                Eh[(size_t)R*1024 + col] = __float2half(acc[r] + bln);
            }
        }
        __syncthreads();
    }
}

// ---------------- keys = enc @ W1 + b1 -> fp16 keysH[b][u][s] ----------------
__global__ __launch_bounds__(256) void keys_kernel(
    const float* __restrict__ enc, const float* __restrict__ W1t,
    const float* __restrict__ b1, __half* __restrict__ keysH)
{
    const int bb = blockIdx.x;
    const int b  = bb >> 3, sq = bb & 7;
    const int tid = threadIdx.x;
    const int u = tid & 127, sh = tid >> 7;
    const int s0 = sq*32 + sh*16;
    float acc[16];
    #pragma unroll
    for(int i = 0; i < 16; ++i) acc[i] = 0.0f;
    const float* wp = W1t + (size_t)u*512;
    const float* xp = enc + (size_t)(b*256 + s0)*512;
    for(int e = 0; e < 512; e += 4){
        float4 wv = *(const float4*)(wp + e);
        #pragma unroll
        for(int i = 0; i < 16; ++i){
            float4 xv = *(const float4*)(xp + (size_t)i*512 + e);
            acc[i] += wv.x*xv.x + wv.y*xv.y + wv.z*xv.z + wv.w*xv.w;
        }
    }
    const float bu = b1[u];
    __half* op = keysH + (size_t)(b*128 + u)*256 + s0;
    #pragma unroll
    for(int i = 0; i < 16; ++i) op[i] = __float2half(acc[i] + bu);
}

// ---------------- persistent decoder: 128 blocks x 512 threads ---------------
__global__ __launch_bounds__(512, 2) void decoder_main(
    const float* __restrict__ W2, const float* __restrict__ b2,
    const float* __restrict__ V, const float* __restrict__ bVp,
    const float* __restrict__ Wo, const float* __restrict__ bop,
    const float* __restrict__ bl2,
    const float* __restrict__ c1_in, const float* __restrict__ c2_in,
    const float* __restrict__ enc, const __half* __restrict__ encH,
    const __half* __restrict__ keysH, const __half* __restrict__ W2h,
    const __half* __restrict__ Eh,
    const uint* __restrict__ WbtH4, const uint* __restrict__ WctH4,
    uint* linD, uint* h1d, uint* h2d,
    float* predacc, int* cnt, float* __restrict__ out, int useEncH)
{
    const int tid  = threadIdx.x;
    const int bid  = blockIdx.x;
    const int ab   = bid;                 // attention batch
    const int lane = tid & 63;
    const int w    = tid >> 6;            // 8 waves
    const int isL  = (bid < 64);          // LSTM blocks
    const int NT   = bid >> 1;            // 32 col-tiles of 32
    const int H    = bid & 1;             // row half (64 batches)
    const int mt   = w >> 1;              // row sub-tile (16)
    const int wc   = w & 1;               // col sub-tile (16)
    const int nn   = lane & 15;
    const int kg   = lane >> 4;
    const int rowA = 64*H + 16*mt + nn;   // MFMA A row / pointwise row
    const int colG = 32*NT + 16*wc + nn;  // MFMA B col
    const int uG   = 8*NT + 4*wc + kg;    // pointwise unit
    const int hIdx = 4*NT + 2*wc + (kg >> 1);

    __shared__ float sh_h2[256], sh_q[128], sh_qp[4][128], sh_sp[2][256];
    __shared__ float sh_at[256], sh_red[8], sh_ctxp[2][512], sh_V[128];
    __shared__ uint  WcS4[8192];          // 32 KB: Wc in MFMA-frag order
    __shared__ float ztS[8*256];          // 8 KB: per-wave z bounce

    if(tid < 128) sh_V[tid] = V[tid];
    const float bVv = bVp[0];
    const float bov = bop[0];

    // LSTM1 weights resident in VGPRs (24 ksteps x 8 halfs)
    v4u wB[24];
    float c1r = 0.0f, c2r = 0.0f, woU = 0.0f;
    float b2i = 0.0f, b2f = 0.0f, b2g = 0.0f, b2o = 0.0f;
    if(isL){
        const uint* wp = WbtH4 + (size_t)colG*384 + kg*4;
        #pragma unroll
        for(int kst = 0; kst < 24; ++kst) wB[kst] = *(const v4u*)(wp + kst*16);
        // Wc into LDS, fragment order [kst][kg][wc][n][4dw]
        for(int it = 0; it < 16; ++it){
            int d = tid + it*512;
            int j4 = d & 3, n_ = (d >> 2) & 15, wcx = (d >> 6) & 1, kgx = (d >> 7) & 3, kstx = d >> 9;
            WcS4[d] = WctH4[(size_t)(32*NT + 16*wcx + n_)*256 + kstx*16 + kgx*4 + j4];
        }
        c1r = c1_in[rowA*256 + uG];
        c2r = c2_in[rowA*256 + uG];
        woU = Wo[uG];
        b2i = bl2[uG]; b2f = bl2[256 + uG]; b2g = bl2[512 + uG]; b2o = bl2[768 + uG];
    }
    __syncthreads();

    for(int t = 0; t < 48; ++t){
        const int rpar = t & 1, wpar = rpar ^ 1;

        // ================= PHASE A : attention (ctx only; emb precomputed) ====
        if(tid < 128){
            uint v = __hip_atomic_load(&h2d[rpar*16384 + ab*128 + tid], __ATOMIC_RELAXED, AGENT);
            float2 f = __half22float2(__builtin_bit_cast(__half2, v));
            sh_h2[2*tid] = f.x; sh_h2[2*tid+1] = f.y;
        }
        __syncthreads();
        if(tid == 0 && t > 0){
            float pv = __hip_atomic_load(&predacc[(t-1)*128 + ab], __ATOMIC_RELAXED, AGENT);
            out[ab*48 + (t-1)] = pv + bov;
        }
        {   // q partials: 4 k-groups x 128 u (W2h fp16, [k][u] row-major)
            const int u = tid & 127, kq = tid >> 7;
            float a = 0.0f;
            const int k0 = kq*64;
            #pragma unroll 8
            for(int i = 0; i < 64; ++i) a += sh_h2[k0 + i]*__half2float(W2h[(size_t)(k0 + i)*128 + u]);
            sh_qp[kq][u] = a;
        }
        __syncthreads();
        if(tid < 128) sh_q[tid] = sh_qp[0][tid] + sh_qp[1][tid] + sh_qp[2][tid] + sh_qp[3][tid] + b2[tid];
        __syncthreads();
        {   // scores: 2 u-halves x 256 s
            const int s = tid & 255, uh = tid >> 8;
            const __half* kp = keysH + (size_t)(ab*128 + uh*64)*256 + s;
            float a = 0.0f;
            #pragma unroll 8
            for(int ui = 0; ui < 64; ++ui)
                a += fast_tanh(__half2float(kp[(size_t)ui*256]) + sh_q[uh*64 + ui]) * sh_V[uh*64 + ui];
            sh_sp[uh][s] = a;
        }
        __syncthreads();
        float sc = 0.0f, pexp = 0.0f;
        if(tid < 256){
            sc = sh_sp[0][tid] + sh_sp[1][tid] + bVv;
            float mx = sc;
            #pragma unroll
            for(int off = 32; off >= 1; off >>= 1) mx = fmaxf(mx, __shfl_xor(mx, off));
            if((tid & 63) == 0) sh_red[tid >> 6] = mx;
        }
        __syncthreads();
        if(tid < 256){
            float mx = fmaxf(fmaxf(sh_red[0], sh_red[1]), fmaxf(sh_red[2], sh_red[3]));
            pexp = __expf(sc - mx);
            float su = pexp;
            #pragma unroll
            for(int off = 32; off >= 1; off >>= 1) su += __shfl_xor(su, off);
            if((tid & 63) == 0) sh_red[4 + (tid >> 6)] = su;
        }
        __syncthreads();
        if(tid < 256) sh_at[tid] = pexp / (sh_red[4] + sh_red[5] + sh_red[6] + sh_red[7]);
        __syncthreads();
        {   // ctx partials: 2 s-halves x 256 e-pairs
            const int e2 = tid & 255, sb = tid >> 8;
            float a0 = 0.0f, a1 = 0.0f;
            if(useEncH){
                const __half2* ep = (const __half2*)encH + (size_t)(ab*256 + sb*128)*256 + e2;
                #pragma unroll 8
                for(int si = 0; si < 128; ++si){
                    float at = sh_at[sb*128 + si];
                    float2 f = __half22float2(ep[(size_t)si*256]);
                    a0 += at*f.x; a1 += at*f.y;
                }
            } else {
                const float2* ep = (const float2*)enc + (size_t)(ab*256 + sb*128)*256 + e2;
                #pragma unroll 8
                for(int si = 0; si < 128; ++si){
                    float at = sh_at[sb*128 + si];
                    float2 f = ep[(size_t)si*256];
                    a0 += at*f.x; a1 += at*f.y;
                }
            }
            sh_ctxp[sb][2*e2] = a0; sh_ctxp[sb][2*e2+1] = a1;
        }
        __syncthreads();
        if(tid < 256){
            __half2 p = __floats2half2_rn(sh_ctxp[0][2*tid] + sh_ctxp[1][2*tid],
                                          sh_ctxp[0][2*tid+1] + sh_ctxp[1][2*tid+1]);
            GSTORE1(linD + ab*256 + tid, __builtin_bit_cast(uint, p));
        }

        // prefetch old-parity h1 frags for B (latency hidden under barrier)
        v4u h1f[8];
        if(isL){
            const uint* hp = h1d + rpar*16384 + rowA*128 + kg*4;
            #pragma unroll
            for(int k8 = 0; k8 < 8; ++k8) GLOAD4(h1f[k8], hp + k8*16);
        }
        gbar(cnt, 3*t + 0, 128);

        // ================= PHASE B : LSTM1 (full-K per wave) ==================
        v4u h2f[8];
        if(isL){
            v4u cf[16];
            const uint* lp = linD + rowA*256 + kg*4;
            #pragma unroll
            for(int kst = 0; kst < 16; ++kst) GLOAD4(cf[kst], lp + kst*16);
            // acc init from E (includes emb@Wx1 + bl1); C rows = 4*kg + r
            const __half* ep = Eh + ((size_t)(t*128 + 64*H + 16*mt + 4*kg))*1024 + colG;
            v4f acc;
            #pragma unroll
            for(int r = 0; r < 4; ++r) acc[r] = __half2float(ep[(size_t)r*1024]);
            #pragma unroll
            for(int k8 = 0; k8 < 8; ++k8)
                acc = __builtin_amdgcn_mfma_f32_16x16x32_f16(
                    __builtin_bit_cast(v8h, h1f[k8]), __builtin_bit_cast(v8h, wB[16 + k8]), acc, 0, 0, 0);
            VMWAIT();
            #pragma unroll
            for(int kst = 0; kst < 16; ++kst)
                acc = __builtin_amdgcn_mfma_f32_16x16x32_f16(
                    __builtin_bit_cast(v8h, cf[kst]), __builtin_bit_cast(v8h, wB[kst]), acc, 0, 0, 0);
            *(v4f*)&ztS[w*256 + nn*16 + 4*kg] = acc;
            // pointwise (same wave; zt slice is wave-private)
            float zi = ztS[w*256 + (4*kg + 0)*16 + nn];
            float zf = ztS[w*256 + (4*kg + 1)*16 + nn];
            float zg = ztS[w*256 + (4*kg + 2)*16 + nn];
            float zo = ztS[w*256 + (4*kg + 3)*16 + nn];
            float cn = fast_sigm(zf)*c1r + fast_sigm(zi)*fast_tanh(zg);
            c1r = cn;
            float hn = fast_sigm(zo)*fast_tanh(cn);
            float hp2 = __shfl_xor(hn, 16);
            if((kg & 1) == 0){
                __half2 ph = __floats2half2_rn(hn, hp2);
                GSTORE1(h1d + wpar*16384 + rowA*128 + hIdx, __builtin_bit_cast(uint, ph));
            }
            // prefetch old-parity h2 frags for C
            const uint* hq = h2d + rpar*16384 + rowA*128 + kg*4;
            #pragma unroll
            for(int k8 = 0; k8 < 8; ++k8) GLOAD4(h2f[k8], hq + k8*16);
        }
        gbar(cnt, 3*t + 1, 128);

        // ================= PHASE C : LSTM2 ====================================
        if(isL){
            v4u nf[8];
            const uint* hp1 = h1d + wpar*16384 + rowA*128 + kg*4;
            #pragma unroll
            for(int k8 = 0; k8 < 8; ++k8) GLOAD4(nf[k8], hp1 + k8*16);
            v4f acc = {0.0f, 0.0f, 0.0f, 0.0f};
            #pragma unroll
            for(int kst = 8; kst < 16; ++kst){   // h2 part first (prefetched)
                v4u wf = *(const v4u*)&WcS4[(((kst*4 + kg)*2 + wc)*16 + nn)*4];
                acc = __builtin_amdgcn_mfma_f32_16x16x32_f16(
                    __builtin_bit_cast(v8h, h2f[kst - 8]), __builtin_bit_cast(v8h, wf), acc, 0, 0, 0);
            }
            VMWAIT();
            #pragma unroll
            for(int kst = 0; kst < 8; ++kst){    // h1n part
                v4u wf = *(const v4u*)&WcS4[(((kst*4 + kg)*2 + wc)*16 + nn)*4];
                acc = __builtin_amdgcn_mfma_f32_16x16x32_f16(
                    __builtin_bit_cast(v8h, nf[kst]), __builtin_bit_cast(v8h, wf), acc, 0, 0, 0);
            }
            *(v4f*)&ztS[w*256 + nn*16 + 4*kg] = acc;
            float zi = ztS[w*256 + (4*kg + 0)*16 + nn] + b2i;
            float zf = ztS[w*256 + (4*kg + 1)*16 + nn] + b2f;
            float zg = ztS[w*256 + (4*kg + 2)*16 + nn] + b2g;
            float zo = ztS[w*256 + (4*kg + 3)*16 + nn] + b2o;
            float cn = fast_sigm(zf)*c2r + fast_sigm(zi)*fast_tanh(zg);
            c2r = cn;
            float hn = fast_sigm(zo)*fast_tanh(cn);
            float hp2 = __shfl_xor(hn, 16);
            if((kg & 1) == 0){
                __half2 ph = __floats2half2_rn(hn, hp2);
                GSTORE1(h2d + wpar*16384 + rowA*128 + hIdx, __builtin_bit_cast(uint, ph));
            }
            // fused pred partial: sum over this block's 4 units (shfl), atomicAdd
            float pv = hn*woU;
            pv += __shfl_xor(pv, 16);
            pv += __shfl_xor(pv, 32);
            if(kg == 0)
                __hip_atomic_fetch_add(&predacc[t*128 + rowA], pv, __ATOMIC_RELAXED, AGENT);
        }
        gbar(cnt, 3*t + 2, 128);
    }

    if(tid == 0){
        float pv = __hip_atomic_load(&predacc[47*128 + ab], __ATOMIC_RELAXED, AGENT);
        out[ab*48 + 47] = pv + bov;
    }
}

extern "C" void kernel_launch(void* const* d_in, const int* in_sizes, int n_in,
                              void* d_out, int out_size, void* d_ws, size_t ws_size,
                              hipStream_t stream)
{
    const float* xdec = (const float*)d_in[0];
    const float* h1_in= (const float*)d_in[1];
    const float* c1_in= (const float*)d_in[2];
    const float* h2_in= (const float*)d_in[3];
    const float* c2_in= (const float*)d_in[4];
    const float* enc  = (const float*)d_in[5];
    const float* embW = (const float*)d_in[6];
    const float* embb = (const float*)d_in[7];
    const float* W1   = (const float*)d_in[8];
    const float* b1   = (const float*)d_in[9];
    const float* W2   = (const float*)d_in[10];
    const float* b2   = (const float*)d_in[11];
    const float* V    = (const float*)d_in[12];
    const float* bV   = (const float*)d_in[13];
    const float* Wx1  = (const float*)d_in[14];
    const float* Wh1  = (const float*)d_in[15];
    const float* bl1  = (const float*)d_in[16];
    const float* Wx2  = (const float*)d_in[17];
    const float* Wh2  = (const float*)d_in[18];
    const float* bl2  = (const float*)d_in[19];
    const float* Wo   = (const float*)d_in[20];
    const float* bo   = (const float*)d_in[21];

    if(ws_size < WS_CORE) return;

    char* ws = (char*)d_ws;
    __half* keysH = (__half*)(ws + OFF_KEYSH);
    __half* WbtH  = (__half*)(ws + OFF_WBT);
    __half* WctH  = (__half*)(ws + OFF_WCT);
    float*  W1t   = (float*) (ws + OFF_W1T);
    __half* W2h   = (__half*)(ws + OFF_W2H);
    __half* Eh    = (__half*)(ws + OFF_EH);
    uint*   linD  = (uint*)  (ws + OFF_LIN);
    uint*   h1d   = (uint*)  (ws + OFF_H1);
    uint*   h2d   = (uint*)  (ws + OFF_H2);
    float*  predacc=(float*) (ws + OFF_PRED);
    int*    cnt   = (int*)   (ws + OFF_CNT);
    __half* encH  = (__half*)(ws + OFF_ENCH);

    const int useEncH = (ws_size >= WS_FULL) ? 1 : 0;
    const long long packTotal = 71936LL + (useEncH ? 4194304LL : 0LL);

    hipLaunchKernelGGL(tpose_kernel, dim3(1344), dim3(256), 0, stream,
        Wx1, Wh1, Wx2, Wh2, W1, WbtH, WctH, W1t);
    hipLaunchKernelGGL(pack_kernel, dim3(2048), dim3(256), 0, stream,
        h1_in, h2_in, W2, enc, h1d, h2d, predacc, cnt, W2h, encH, packTotal);
    hipLaunchKernelGGL(embE_kernel, dim3(384), dim3(256), 0, stream,
        xdec, embW, embb, Wx1, bl1, Eh);
    hipLaunchKernelGGL(keys_kernel, dim3(1024), dim3(256), 0, stream,
        enc, W1t, b1, keysH);
    hipLaunchKernelGGL(decoder_main, dim3(128), dim3(512), 0, stream,
        W2, b2, V, bV, Wo, bo, bl2, c1_in, c2_in, enc, encH,
        keysH, W2h, Eh, (const uint*)WbtH, (const uint*)WctH,
        linD, h1d, h2d, predacc, cnt, (float*)d_out, useEncH);
}

// Round 6
// 2970.116 us; speedup vs baseline: 1.5813x; 1.5813x over previous
//
#include <hip/hip_runtime.h>
#include <hip/hip_fp16.h>

#define AGENT __HIP_MEMORY_SCOPE_AGENT

typedef _Float16 v8h __attribute__((ext_vector_type(8)));
typedef float    v4f __attribute__((ext_vector_type(4)));
typedef unsigned int uint;

// ---- workspace map (bytes); WS_CORE ~12.6MB << 24.5MB proven available ----
#define OFF_KEYSH  0UL            // half [128 b][128 u][256 s]      8,388,608
#define OFF_WBT    8388608UL      // half [1024 c][1024 k]           2,097,152
#define OFF_WCT    10485760UL     // half [1024 c][512 k]            1,048,576
#define OFF_W1T    11534336UL     // f32  [128 u][512 e]               262,144
#define OFF_LIN    11796480UL     // uint [128 b][384 dw]              196,608
#define OFF_H1     11993088UL     // uint [2][128][128]                131,072
#define OFF_H2     12124160UL     // uint [2][128][128]                131,072
#define OFF_CNT    12255232UL     // int  [144][512]                   294,912
#define WS_CORE    12550144UL
#define OFF_ENCH   12550144UL     // half [128][256][512]           33,554,432
#define WS_FULL    46104576UL

static __device__ __forceinline__ float fast_tanh(float x){
    float e = __expf(2.0f*x);
    return 1.0f - 2.0f*__builtin_amdgcn_rcpf(e + 1.0f);
}
static __device__ __forceinline__ float fast_sigm(float x){
    return __builtin_amdgcn_rcpf(1.0f + __expf(-x));
}

// Hierarchical fence-free grid barrier. PROVEN semantics from rounds 2/3:
// s_waitcnt(0) drain + relaxed agent-scope atomic RMW (coherence-point op).
// Rounds 4/5 proved plain-store flags + plain-load polls are NOT a sound
// barrier on this chip (nondeterministic stale reads) — do not regress.
// Two levels cut same-line RMW serialization 128 -> 8 (groups) + 16 (root).
static __device__ __forceinline__ void gbar(int* cnt, int idx, int bid){
    __builtin_amdgcn_s_waitcnt(0);
    __syncthreads();
    if(threadIdx.x == 0){
        int* base = cnt + idx*512;
        int* gc = base + (bid >> 3)*16;      // own 64B line per 8-block group
        int* rc = base + 496;                // root line
        int prev = __hip_atomic_fetch_add(gc, 1, __ATOMIC_RELAXED, AGENT);
        if(prev == 7)
            __hip_atomic_fetch_add(rc, 1, __ATOMIC_RELAXED, AGENT);
        while(__hip_atomic_load(rc, __ATOMIC_RELAXED, AGENT) < 16)
            __builtin_amdgcn_s_sleep(1);
    }
    __syncthreads();
}

// ---------------- tiled transposes: WbtH [c][1024], WctH [c][512], W1t ------
// Same output layouts as round-2's proven consumer: c = 4*unit + gate,
// Wbt k-order = [Wx1 rows 0..767 (emb|ctx) | Wh1 rows 0..255],
// Wct k-order = [Wx2 rows 0..255 | Wh2 rows 0..255].
__global__ __launch_bounds__(256) void tpose_kernel(
    const float* __restrict__ Wx1, const float* __restrict__ Wh1,
    const float* __restrict__ Wx2, const float* __restrict__ Wh2,
    const float* __restrict__ W1,
    __half* __restrict__ WbtH, __half* __restrict__ WctH, float* __restrict__ W1t)
{
    __shared__ float T[32][33];
    const int bid = blockIdx.x, tid = threadIdx.x;
    if(bid < 1024){                             // Wbt: k 1024 x n 1024
        const int kt = bid >> 5, nt = bid & 31;
        const int k0 = kt*32, n0 = nt*32;
        const int ty = tid >> 5, tx = tid & 31;
        for(int r = 0; r < 4; ++r){
            int k = k0 + ty*4 + r, n = n0 + tx;
            float v = (k < 768) ? Wx1[(size_t)k*1024 + n] : Wh1[(size_t)(k-768)*1024 + n];
            T[ty*4 + r][tx] = v;
        }
        __syncthreads();
        const int nl = tid >> 3, kc = tid & 7;
        const int n = n0 + nl;
        const int c = 4*(n & 255) + (n >> 8);
        __half h[4];
        for(int j = 0; j < 4; ++j) h[j] = __float2half(T[kc*4 + j][nl]);
        *(uint2*)&WbtH[(size_t)c*1024 + k0 + kc*4] = *(uint2*)h;
    } else if(bid < 1536){                      // Wct: k 512 x n 1024
        const int i = bid - 1024;
        const int kt = i >> 5, nt = i & 31;
        const int k0 = kt*32, n0 = nt*32;
        const int ty = tid >> 5, tx = tid & 31;
        for(int r = 0; r < 4; ++r){
            int k = k0 + ty*4 + r, n = n0 + tx;
            float v = (k < 256) ? Wx2[(size_t)k*1024 + n] : Wh2[(size_t)(k-256)*1024 + n];
            T[ty*4 + r][tx] = v;
        }
        __syncthreads();
        const int nl = tid >> 3, kc = tid & 7;
        const int n = n0 + nl;
        const int c = 4*(n & 255) + (n >> 8);
        __half h[4];
        for(int j = 0; j < 4; ++j) h[j] = __float2half(T[kc*4 + j][nl]);
        *(uint2*)&WctH[(size_t)c*512 + k0 + kc*4] = *(uint2*)h;
    } else {                                    // W1t [u][e] <- W1[e 512][u 128]
        const int i = bid - 1536;
        const int ut = i >> 4, et = i & 15;
        const int e0 = et*32, u0 = ut*32;
        const int ty = tid >> 5, tx = tid & 31;
        for(int r = 0; r < 4; ++r){
            int e = e0 + ty*4 + r, u = u0 + tx;
            T[ty*4 + r][tx] = W1[(size_t)e*128 + u];
        }
        __syncthreads();
        const int ul = tid >> 3, ec = tid & 7;
        float4 f;
        f.x = T[ec*4+0][ul]; f.y = T[ec*4+1][ul]; f.z = T[ec*4+2][ul]; f.w = T[ec*4+3][ul];
        *(float4*)&W1t[(size_t)(u0+ul)*512 + e0 + ec*4] = f;
    }
}

// ---------------- pack: states (fp16 pairs), counters, encH -----------------
__global__ __launch_bounds__(256) void pack_kernel(
    const float* __restrict__ h1_in, const float* __restrict__ h2_in,
    const float* __restrict__ enc,
    uint* __restrict__ h1d, uint* __restrict__ h2d,
    int* __restrict__ cnt, __half* __restrict__ encH, long long total)
{
    long long id0 = (long long)blockIdx.x*blockDim.x + threadIdx.x;
    long long stride = (long long)gridDim.x*blockDim.x;
    for(long long id = id0; id < total; id += stride){
        if(id < 16384LL){                        // h1d parity 0
            int b = (int)(id >> 7), j = (int)(id & 127);
            __half2 p = __floats2half2_rn(h1_in[b*256 + 2*j], h1_in[b*256 + 2*j + 1]);
            h1d[id] = __builtin_bit_cast(uint, p);
        } else if(id < 32768LL){                 // h2d parity 0
            long long i = id - 16384LL;
            int b = (int)(i >> 7), j = (int)(i & 127);
            __half2 p = __floats2half2_rn(h2_in[b*256 + 2*j], h2_in[b*256 + 2*j + 1]);
            h2d[i] = __builtin_bit_cast(uint, p);
        } else if(id < 106496LL){                // cnt[144][512] = 0
            cnt[(int)(id - 32768LL)] = 0;
        } else {                                 // encH float4 chunks
            long long c = id - 106496LL;
            float4 f = *(const float4*)&enc[c*4];
            __half2 p0 = __floats2half2_rn(f.x, f.y);
            __half2 p1 = __floats2half2_rn(f.z, f.w);
            uint2 u; u.x = __builtin_bit_cast(uint, p0); u.y = __builtin_bit_cast(uint, p1);
            *(uint2*)&encH[c*4] = u;
        }
    }
}

// ---------------- keys = enc @ W1 + b1 -> fp16 keysH[b][u][s] ---------------
__global__ __launch_bounds__(256) void keys_kernel(
    const float* __restrict__ enc, const float* __restrict__ W1t,
    const float* __restrict__ b1, __half* __restrict__ keysH)
{
    const int bb = blockIdx.x;
    const int b  = bb >> 3, sq = bb & 7;
    const int tid = threadIdx.x;
    const int u = tid & 127, sh = tid >> 7;
    const int s0 = sq*32 + sh*16;
    float acc[16];
    #pragma unroll
    for(int i = 0; i < 16; ++i) acc[i] = 0.0f;
    const float* wp = W1t + (size_t)u*512;
    const float* xp = enc + (size_t)(b*256 + s0)*512;
    for(int e = 0; e < 512; e += 4){
        float4 wv = *(const float4*)(wp + e);
        #pragma unroll
        for(int i = 0; i < 16; ++i){
            float4 xv = *(const float4*)(xp + (size_t)i*512 + e);
            acc[i] += wv.x*xv.x + wv.y*xv.y + wv.z*xv.z + wv.w*xv.w;
        }
    }
    const float bu = b1[u];
    __half* op = keysH + (size_t)(b*128 + u)*256 + s0;
    #pragma unroll
    for(int i = 0; i < 16; ++i) op[i] = __float2half(acc[i] + bu);
}

// ---------------- persistent decoder: 128 blocks x 1024 threads --------------
// VERBATIM round-2 decoder (passed, absmax 1.95e-3) except gbar -> hierarchical.
__global__ __launch_bounds__(1024) void decoder_main(
    const float* __restrict__ xdec, const float* __restrict__ embW, const float* __restrict__ embb,
    const float* __restrict__ W2, const float* __restrict__ b2,
    const float* __restrict__ V, const float* __restrict__ bVp,
    const float* __restrict__ Wo, const float* __restrict__ bop,
    const float* __restrict__ bl1, const float* __restrict__ bl2,
    const float* __restrict__ c1_in, const float* __restrict__ c2_in,
    const float* __restrict__ enc, const __half* __restrict__ encH,
    const __half* __restrict__ keysH,
    const __half* __restrict__ WbtH, const __half* __restrict__ WctH,
    uint* linD, uint* h1d, uint* h2d,
    int* cnt, float* __restrict__ out, int useEncH)
{
    const int tid = threadIdx.x;
    const int ab  = blockIdx.x;              // attention batch for this block
    const int NT  = blockIdx.x >> 1;         // col tile: cols 16NT..16NT+15 (units 4NT..4NT+3)
    const int H   = blockIdx.x & 1;          // batch half: 64H..64H+63
    const int w    = tid >> 6;               // wave 0..15 (= K-split index)
    const int lane = tid & 63;
    const int cl   = lane & 15;              // MFMA m-row / n-col / C-col
    const int kg   = lane >> 4;              // MFMA k-quad
    const int uu   = lane >> 4;              // pointwise unit-local
    const int bl   = lane & 15;              // pointwise batch-local

    __shared__ float zb[16][16][20];         // per-wave z partial tiles
    __shared__ float sh_h2[256];
    __shared__ float sh_q[128];
    __shared__ float sh_qp[8][128];
    __shared__ float sh_sp[4][256];
    __shared__ float sh_at[256];
    __shared__ float sh_red[16];
    __shared__ float sh_ctxp[2][512];
    __shared__ float sh_V[128];

    if(tid < 128) sh_V[tid] = V[tid];
    const float bVv = bVp[0];
    const float bov = bop[0];

    // ---- weights resident in VGPRs for all 48 steps ----
    const __half* wbp = WbtH + ((size_t)(16*NT + cl)*1024 + w*64 + kg*8);
    v8h wb1a = __builtin_bit_cast(v8h, *(const uint4*)(wbp));
    v8h wb1b = __builtin_bit_cast(v8h, *(const uint4*)(wbp + 32));
    const __half* wcp = WctH + ((size_t)(16*NT + cl)*512 + w*32 + kg*8);
    v8h wc1  = __builtin_bit_cast(v8h, *(const uint4*)(wcp));

    // ---- per-lane cell state + gate biases (only waves 0..3 own pointwise) ----
    const int ug = 4*NT + uu;
    float bi1 = bl1[ug], bf1 = bl1[256+ug], bg1 = bl1[512+ug], bo1 = bl1[768+ug];
    float bi2 = bl2[ug], bf2 = bl2[256+ug], bg2 = bl2[512+ug], bo2 = bl2[768+ug];
    float c1r = 0.0f, c2r = 0.0f;
    if(w < 4){
        int bb = 64*H + 16*w + bl;
        c1r = c1_in[bb*256 + ug];
        c2r = c2_in[bb*256 + ug];
    }
    __syncthreads();

    for(int t = 0; t < 48; ++t){
        const int rpar = t & 1, wpar = rpar ^ 1;
        uint* h1r = h1d + rpar*16384;
        uint* h1w = h1d + wpar*16384;
        uint* h2r = h2d + rpar*16384;
        uint* h2w = h2d + wpar*16384;

        // ================= PHASE A : attention + pred(t-1) + emb =================
        if(tid < 128){
            uint v = __hip_atomic_load(&h2r[ab*128 + tid], __ATOMIC_RELAXED, AGENT);
            float2 f = __half22float2(__builtin_bit_cast(__half2, v));
            sh_h2[2*tid] = f.x; sh_h2[2*tid+1] = f.y;
            float pv = f.x*Wo[2*tid] + f.y*Wo[2*tid+1];
            #pragma unroll
            for(int off = 32; off >= 1; off >>= 1) pv += __shfl_xor(pv, off);
            if((tid & 63) == 0) sh_red[8 + (tid >> 6)] = pv;
        }
        __syncthreads();
        if(tid == 0 && t > 0) out[ab*48 + (t-1)] = sh_red[8] + sh_red[9] + bov;
        {   // q partials: 8 k-groups x 128 u
            const int u = tid & 127, kq8 = tid >> 7;
            float a = 0.0f;
            const int k0 = kq8*32;
            #pragma unroll 8
            for(int k = k0; k < k0 + 32; ++k) a += sh_h2[k]*W2[k*128 + u];
            sh_qp[kq8][u] = a;
        }
        __syncthreads();
        if(tid < 128){
            float a = b2[tid];
            #pragma unroll
            for(int j = 0; j < 8; ++j) a += sh_qp[j][tid];
            sh_q[tid] = a;
        }
        __syncthreads();
        {   // score partials: 4 u-quarters x 256 s
            const int s = tid & 255, uq = tid >> 8;
            const __half* kp = keysH + ((size_t)(ab*128 + uq*32)*256 + s);
            float a = 0.0f;
            #pragma unroll 8
            for(int ui = 0; ui < 32; ++ui)
                a += fast_tanh(__half2float(kp[(size_t)ui*256]) + sh_q[uq*32 + ui]) * sh_V[uq*32 + ui];
            sh_sp[uq][s] = a;
        }
        __syncthreads();
        float sc = 0.0f, pexp = 0.0f;
        if(tid < 256){
            sc = sh_sp[0][tid] + sh_sp[1][tid] + sh_sp[2][tid] + sh_sp[3][tid] + bVv;
            float mx = sc;
            #pragma unroll
            for(int off = 32; off >= 1; off >>= 1) mx = fmaxf(mx, __shfl_xor(mx, off));
            if((tid & 63) == 0) sh_red[tid >> 6] = mx;
        }
        __syncthreads();
        if(tid < 256){
            float mx = fmaxf(fmaxf(sh_red[0], sh_red[1]), fmaxf(sh_red[2], sh_red[3]));
            pexp = __expf(sc - mx);
            float su = pexp;
            #pragma unroll
            for(int off = 32; off >= 1; off >>= 1) su += __shfl_xor(su, off);
            if((tid & 63) == 0) sh_red[4 + (tid >> 6)] = su;
        }
        __syncthreads();
        if(tid < 256){
            float su = sh_red[4] + sh_red[5] + sh_red[6] + sh_red[7];
            sh_at[tid] = pexp / su;
        }
        __syncthreads();
        {   // ctx partials: 2 s-halves x 512 e
            const int e = tid & 511, s2 = tid >> 9;
            float a = 0.0f;
            if(useEncH){
                const __half* ep = encH + ((size_t)(ab*256 + s2*128)*512 + e);
                #pragma unroll 8
                for(int si = 0; si < 128; ++si) a += sh_at[s2*128 + si]*__half2float(ep[(size_t)si*512]);
            } else {
                const float* ep = enc + ((size_t)(ab*256 + s2*128)*512 + e);
                #pragma unroll 8
                for(int si = 0; si < 128; ++si) a += sh_at[s2*128 + si]*ep[(size_t)si*512];
            }
            sh_ctxp[s2][e] = a;
        }
        __syncthreads();
        if(tid < 384){  // lin row: dw 0..127 = emb(relu), 128..383 = ctx
            float e0, e1;
            if(tid < 128){
                float x = xdec[ab*48 + t];
                e0 = fmaxf(x*embW[2*tid]   + embb[2*tid],   0.0f);
                e1 = fmaxf(x*embW[2*tid+1] + embb[2*tid+1], 0.0f);
            } else {
                int e = 2*(tid - 128);
                e0 = sh_ctxp[0][e]   + sh_ctxp[1][e];
                e1 = sh_ctxp[0][e+1] + sh_ctxp[1][e+1];
            }
            __half2 p = __floats2half2_rn(e0, e1);
            __hip_atomic_store(&linD[ab*384 + tid], __builtin_bit_cast(uint, p),
                               __ATOMIC_RELAXED, AGENT);
        }
        gbar(cnt, 3*t + 0, ab);

        // ================= PHASE B : LSTM1 (MFMA, 16-way K-split) =================
        {
            uint pf[4][8];
            #pragma unroll
            for(int mt = 0; mt < 4; ++mt){
                const int row = 64*H + 16*mt + cl;
                #pragma unroll
                for(int kt = 0; kt < 2; ++kt){
                    const int d0 = w*32 + kt*16 + kg*4;
                    const uint* src; int di;
                    if(d0 < 384){ src = linD + row*384; di = d0; }
                    else        { src = h1r  + row*128; di = d0 - 384; }
                    #pragma unroll
                    for(int j = 0; j < 4; ++j)
                        pf[mt][kt*4 + j] = __hip_atomic_load(&src[di + j], __ATOMIC_RELAXED, AGENT);
                }
            }
            #pragma unroll
            for(int mt = 0; mt < 4; ++mt){
                v4f acc = {0.0f, 0.0f, 0.0f, 0.0f};
                uint4 ua0 = make_uint4(pf[mt][0], pf[mt][1], pf[mt][2], pf[mt][3]);
                uint4 ua1 = make_uint4(pf[mt][4], pf[mt][5], pf[mt][6], pf[mt][7]);
                acc = __builtin_amdgcn_mfma_f32_16x16x32_f16(__builtin_bit_cast(v8h, ua0), wb1a, acc, 0, 0, 0);
                acc = __builtin_amdgcn_mfma_f32_16x16x32_f16(__builtin_bit_cast(v8h, ua1), wb1b, acc, 0, 0, 0);
                #pragma unroll
                for(int r = 0; r < 4; ++r) zb[w][kg*4 + r][cl] = acc[r];
                __syncthreads();
                if(w == mt){
                    v4f z = {0.0f, 0.0f, 0.0f, 0.0f};
                    #pragma unroll
                    for(int q = 0; q < 16; ++q) z += *(const v4f*)&zb[q][bl][uu*4];
                    float cn = fast_sigm(z.y + bf1)*c1r + fast_sigm(z.x + bi1)*fast_tanh(z.z + bg1);
                    c1r = cn;
                    float hn = fast_sigm(z.w + bo1)*fast_tanh(cn);
                    float hp = __shfl_xor(hn, 16);
                    if((uu & 1) == 0){
                        __half2 ph = __floats2half2_rn(hn, hp);
                        int bb = 64*H + 16*mt + bl;
                        __hip_atomic_store(&h1w[bb*128 + 2*NT + (uu >> 1)],
                                           __builtin_bit_cast(uint, ph),
                                           __ATOMIC_RELAXED, AGENT);
                    }
                }
                __syncthreads();
            }
        }
        gbar(cnt, 3*t + 1, ab);

        // ================= PHASE C : LSTM2 (MFMA, 16-way K-split) =================
        {
            uint pf2[4][4];
            #pragma unroll
            for(int mt = 0; mt < 4; ++mt){
                const int row = 64*H + 16*mt + cl;
                const int d0 = w*16 + kg*4;
                const uint* src; int di;
                if(d0 < 128){ src = h1w + row*128; di = d0; }
                else        { src = h2r + row*128; di = d0 - 128; }
                #pragma unroll
                for(int j = 0; j < 4; ++j)
                    pf2[mt][j] = __hip_atomic_load(&src[di + j], __ATOMIC_RELAXED, AGENT);
            }
            #pragma unroll
            for(int mt = 0; mt < 4; ++mt){
                v4f acc = {0.0f, 0.0f, 0.0f, 0.0f};
                uint4 ua = make_uint4(pf2[mt][0], pf2[mt][1], pf2[mt][2], pf2[mt][3]);
                acc = __builtin_amdgcn_mfma_f32_16x16x32_f16(__builtin_bit_cast(v8h, ua), wc1, acc, 0, 0, 0);
                #pragma unroll
                for(int r = 0; r < 4; ++r) zb[w][kg*4 + r][cl] = acc[r];
                __syncthreads();
                if(w == mt){
                    v4f z = {0.0f, 0.0f, 0.0f, 0.0f};
                    #pragma unroll
                    for(int q = 0; q < 16; ++q) z += *(const v4f*)&zb[q][bl][uu*4];
                    float cn = fast_sigm(z.y + bf2)*c2r + fast_sigm(z.x + bi2)*fast_tanh(z.z + bg2);
                    c2r = cn;
                    float hn = fast_sigm(z.w + bo2)*fast_tanh(cn);
                    float hp = __shfl_xor(hn, 16);
                    if((uu & 1) == 0){
                        __half2 ph = __floats2half2_rn(hn, hp);
                        int bb = 64*H + 16*mt + bl;
                        __hip_atomic_store(&h2w[bb*128 + 2*NT + (uu >> 1)],
                                           __builtin_bit_cast(uint, ph),
                                           __ATOMIC_RELAXED, AGENT);
                    }
                }
                __syncthreads();
            }
        }
        gbar(cnt, 3*t + 2, ab);
    }

    // final pred (t=47): h2 now at parity 0
    {
        float pv = 0.0f;
        if(tid < 128){
            uint v = __hip_atomic_load(&h2d[ab*128 + tid], __ATOMIC_RELAXED, AGENT);
            float2 f = __half22float2(__builtin_bit_cast(__half2, v));
            pv = f.x*Wo[2*tid] + f.y*Wo[2*tid+1];
            #pragma unroll
            for(int off = 32; off >= 1; off >>= 1) pv += __shfl_xor(pv, off);
            if((tid & 63) == 0) sh_red[tid >> 6] = pv;
        }
        __syncthreads();
        if(tid == 0) out[ab*48 + 47] = sh_red[0] + sh_red[1] + bov;
    }
}

extern "C" void kernel_launch(void* const* d_in, const int* in_sizes, int n_in,
                              void* d_out, int out_size, void* d_ws, size_t ws_size,
                              hipStream_t stream)
{
    const float* xdec = (const float*)d_in[0];
    const float* h1_in= (const float*)d_in[1];
    const float* c1_in= (const float*)d_in[2];
    const float* h2_in= (const float*)d_in[3];
    const float* c2_in= (const float*)d_in[4];
    const float* enc  = (const float*)d_in[5];
    const float* embW = (const float*)d_in[6];
    const float* embb = (const float*)d_in[7];
    const float* W1   = (const float*)d_in[8];
    const float* b1   = (const float*)d_in[9];
    const float* W2   = (const float*)d_in[10];
    const float* b2   = (const float*)d_in[11];
    const float* V    = (const float*)d_in[12];
    const float* bV   = (const float*)d_in[13];
    const float* Wx1  = (const float*)d_in[14];
    const float* Wh1  = (const float*)d_in[15];
    const float* bl1  = (const float*)d_in[16];
    const float* Wx2  = (const float*)d_in[17];
    const float* Wh2  = (const float*)d_in[18];
    const float* bl2  = (const float*)d_in[19];
    const float* Wo   = (const float*)d_in[20];
    const float* bo   = (const float*)d_in[21];

    if(ws_size < WS_CORE) return;

    char* ws = (char*)d_ws;
    __half* keysH = (__half*)(ws + OFF_KEYSH);
    __half* WbtH  = (__half*)(ws + OFF_WBT);
    __half* WctH  = (__half*)(ws + OFF_WCT);
    float*  W1t   = (float*) (ws + OFF_W1T);
    uint*   linD  = (uint*)  (ws + OFF_LIN);
    uint*   h1d   = (uint*)  (ws + OFF_H1);
    uint*   h2d   = (uint*)  (ws + OFF_H2);
    int*    cnt   = (int*)   (ws + OFF_CNT);
    __half* encH  = (__half*)(ws + OFF_ENCH);

    const int useEncH = (ws_size >= WS_FULL) ? 1 : 0;
    const long long packTotal = 106496LL + (useEncH ? 4194304LL : 0LL);

    hipLaunchKernelGGL(tpose_kernel, dim3(1600), dim3(256), 0, stream,
        Wx1, Wh1, Wx2, Wh2, W1, WbtH, WctH, W1t);
    hipLaunchKernelGGL(pack_kernel, dim3(2048), dim3(256), 0, stream,
        h1_in, h2_in, enc, h1d, h2d, cnt, encH, packTotal);
    hipLaunchKernelGGL(keys_kernel, dim3(1024), dim3(256), 0, stream,
        enc, W1t, b1, keysH);
    hipLaunchKernelGGL(decoder_main, dim3(128), dim3(1024), 0, stream,
        xdec, embW, embb, W2, b2, V, bV, Wo, bo, bl1, bl2,
        c1_in, c2_in, enc, encH, keysH, WbtH, WctH,
        linD, h1d, h2d, cnt, (float*)d_out, useEncH);
}